// Round 1
// baseline (112.786 us; speedup 1.0000x reference)
//
#include <hip/hip_runtime.h>

#define PI_HALF_F 1.57079632679489661923f

__global__ __launch_bounds__(256) void quantum_kernel(
    const float* __restrict__ x,
    const float* __restrict__ theta,
    float* __restrict__ out,
    int B)
{
    // ---- per-block: build the 16 shared Rot gate matrices in LDS ----
    __shared__ float g[16][8];  // [layer*8+q][u00r,u00i,u01r,u01i,u10r,u10i,u11r,u11i]
    const int t = threadIdx.x;
    if (t < 16) {
        const int layer = t >> 3, q = t & 7;
        const float phi = theta[(layer * 8 + q) * 3 + 0];
        const float th  = theta[(layer * 8 + q) * 3 + 1];
        const float om  = theta[(layer * 8 + q) * 3 + 2];
        const float ct = __cosf(0.5f * th), st = __sinf(0.5f * th);
        const float a = 0.5f * (phi + om), b = 0.5f * (phi - om);
        const float ca = __cosf(a), sa = __sinf(a);
        const float cb = __cosf(b), sb = __sinf(b);
        g[t][0] =  ct * ca;  g[t][1] = -ct * sa;   // u00 = e^{-ia} ct
        g[t][2] = -st * cb;  g[t][3] = -st * sb;   // u01 = -e^{+ib} st
        g[t][4] =  st * cb;  g[t][5] = -st * sb;   // u10 = e^{-ib} st
        g[t][6] =  ct * ca;  g[t][7] =  ct * sa;   // u11 = e^{+ia} ct
    }
    __syncthreads();

    const int tid = blockIdx.x * 256 + t;
    const int sample = tid >> 4;       // 16 lanes per sample
    if (sample >= B) return;
    const int sub = t & 15;            // lane bits l3..l0 <-> qubits 0..3
    const int lane = t & 63;

    // ---- load x[8], compute encoding factors ----
    const float4* xp = reinterpret_cast<const float4*>(x + sample * 8);
    const float4 xa = xp[0], xb = xp[1];
    float xs[8] = {xa.x, xa.y, xa.z, xa.w, xb.x, xb.y, xb.z, xb.w};
    float cq[8], sq[8];
#pragma unroll
    for (int q = 0; q < 8; ++q) {
        float v = fminf(fmaxf(xs[q], -1.0f), 1.0f) * PI_HALF_F;
        cq[q] = __cosf(v);
        sq[q] = __sinf(v);
    }

    // ---- init product state after RY encoding (all real) ----
    // index bits: [7:4]=sub (qubits 0..3), [3:0]=r (qubits 4..7)
    const float fa0 = (sub & 8) ? sq[0] : cq[0];
    const float fa1 = (sub & 4) ? sq[1] : cq[1];
    const float fa2 = (sub & 2) ? sq[2] : cq[2];
    const float fa3 = (sub & 1) ? sq[3] : cq[3];
    const float plane = fa0 * fa1 * fa2 * fa3;

    float h45[4], h67[4];
#pragma unroll
    for (int k = 0; k < 4; ++k) {
        h45[k] = ((k & 2) ? sq[4] : cq[4]) * ((k & 1) ? sq[5] : cq[5]) * plane;
        h67[k] = ((k & 2) ? sq[6] : cq[6]) * ((k & 1) ? sq[7] : cq[7]);
    }
    float re[16], im[16];
#pragma unroll
    for (int r = 0; r < 16; ++r) { re[r] = h45[r >> 2] * h67[r & 3]; im[r] = 0.0f; }

    // ---- variational layers ----
#pragma unroll
    for (int layer = 0; layer < 2; ++layer) {
        // --- Rot gates on qubits 0..7 ---
#pragma unroll
        for (int q = 0; q < 8; ++q) {
            const float4 ga = *reinterpret_cast<const float4*>(&g[layer * 8 + q][0]);
            const float4 gb = *reinterpret_cast<const float4*>(&g[layer * 8 + q][4]);
            const float u00r = ga.x, u00i = ga.y, u01r = ga.z, u01i = ga.w;
            const float u10r = gb.x, u10i = gb.y, u11r = gb.z, u11i = gb.w;
            if (q < 4) {
                // cross-lane gate: lane mask
                const int m = 8 >> q;
                const bool hi = (sub & m) != 0;
                const float car = hi ? u11r : u00r, cai = hi ? u11i : u00i;  // coeff on my amp
                const float cbr = hi ? u10r : u01r, cbi = hi ? u10i : u01i;  // coeff on partner amp
#pragma unroll
                for (int r = 0; r < 16; ++r) {
                    const float pr  = __shfl_xor(re[r], m);
                    const float pi_ = __shfl_xor(im[r], m);
                    const float nr = car * re[r] - cai * im[r] + cbr * pr - cbi * pi_;
                    const float ni = car * im[r] + cai * re[r] + cbr * pi_ + cbi * pr;
                    re[r] = nr; im[r] = ni;
                }
            } else {
                // in-register gate: register bit p = 7-q
                const int pm = 1 << (7 - q);
#pragma unroll
                for (int r = 0; r < 16; ++r) {
                    if (!(r & pm)) {
                        const int r1 = r | pm;
                        const float a0r = re[r],  a0i = im[r];
                        const float a1r = re[r1], a1i = im[r1];
                        re[r]  = u00r * a0r - u00i * a0i + u01r * a1r - u01i * a1i;
                        im[r]  = u00r * a0i + u00i * a0r + u01r * a1i + u01i * a1r;
                        re[r1] = u10r * a0r - u10i * a0i + u11r * a1r - u11i * a1i;
                        im[r1] = u10r * a0i + u10i * a0r + u11r * a1i + u11i * a1r;
                    }
                }
            }
        }

        // --- CNOT chain c=0..6 (control c, target c+1) ---
        // c=0,1,2: control & target both lane bits -> computed-source shuffle
#pragma unroll
        for (int c = 0; c < 3; ++c) {
            const int cm = 8 >> c, tm = 4 >> c;
            const int src = (sub & cm) ? (lane ^ tm) : lane;
#pragma unroll
            for (int r = 0; r < 16; ++r) {
                re[r] = __shfl(re[r], src);
                im[r] = __shfl(im[r], src);
            }
        }
        // c=3: control = lane bit0, target = register bit3 -> predicated reg swap
        {
            const bool cc = (sub & 1) != 0;
#pragma unroll
            for (int r = 0; r < 8; ++r) {
                const float tr = re[r], ti = im[r];
                re[r]     = cc ? re[r + 8] : re[r];
                im[r]     = cc ? im[r + 8] : im[r];
                re[r + 8] = cc ? tr : re[r + 8];
                im[r + 8] = cc ? ti : im[r + 8];
            }
        }
        // c=4: ctrl r-bit3, tgt r-bit2: swap (r, r^4) for r&8
#pragma unroll
        for (int r = 8; r < 12; ++r) {
            float tr = re[r]; re[r] = re[r + 4]; re[r + 4] = tr;
            float ti = im[r]; im[r] = im[r + 4]; im[r + 4] = ti;
        }
        // c=5: ctrl r-bit2, tgt r-bit1: swap (4,6),(5,7),(12,14),(13,15)
        {
            const int a0[4] = {4, 5, 12, 13};
#pragma unroll
            for (int k = 0; k < 4; ++k) {
                const int r = a0[k];
                float tr = re[r]; re[r] = re[r + 2]; re[r + 2] = tr;
                float ti = im[r]; im[r] = im[r + 2]; im[r + 2] = ti;
            }
        }
        // c=6: ctrl r-bit1, tgt r-bit0: swap (2,3),(6,7),(10,11),(14,15)
        {
            const int a0[4] = {2, 6, 10, 14};
#pragma unroll
            for (int k = 0; k < 4; ++k) {
                const int r = a0[k];
                float tr = re[r]; re[r] = re[r + 1]; re[r + 1] = tr;
                float ti = im[r]; im[r] = im[r + 1]; im[r + 1] = ti;
            }
        }
    }

    // ---- expectation values ----
    float p[16];
#pragma unroll
    for (int r = 0; r < 16; ++r) p[r] = re[r] * re[r] + im[r] * im[r];

    const float e0 = p[0] + p[1],  e1 = p[2] + p[3];
    const float e2 = p[4] + p[5],  e3 = p[6] + p[7];
    const float e4 = p[8] + p[9],  e5 = p[10] + p[11];
    const float e6 = p[12] + p[13], e7 = p[14] + p[15];
    const float q0 = e0 + e1, q1 = e2 + e3, q2 = e4 + e5, q3 = e6 + e7;
    const float u0 = q0 + q1, u1 = q2 + q3;
    const float s_all = u0 + u1;

    float z4 = u0 - u1;                                  // qubit 4 <-> r bit 3
    float z5 = (q0 - q1) + (q2 - q3);                    // qubit 5 <-> r bit 2
    float z6 = (e0 - e1) + (e2 - e3) + (e4 - e5) + (e6 - e7);  // qubit 6 <-> r bit 1
    float z7 = (p[0] - p[1]) + (p[2] - p[3]) + (p[4] - p[5]) + (p[6] - p[7])
             + (p[8] - p[9]) + (p[10] - p[11]) + (p[12] - p[13]) + (p[14] - p[15]);
    float z0 = (sub & 8) ? -s_all : s_all;
    float z1 = (sub & 4) ? -s_all : s_all;
    float z2 = (sub & 2) ? -s_all : s_all;
    float z3 = (sub & 1) ? -s_all : s_all;

    // butterfly reduce over the 16-lane group
#pragma unroll
    for (int m = 1; m < 16; m <<= 1) {
        z0 += __shfl_xor(z0, m);
        z1 += __shfl_xor(z1, m);
        z2 += __shfl_xor(z2, m);
        z3 += __shfl_xor(z3, m);
        z4 += __shfl_xor(z4, m);
        z5 += __shfl_xor(z5, m);
        z6 += __shfl_xor(z6, m);
        z7 += __shfl_xor(z7, m);
    }

    if (sub < 8) {
        float v = z0;
        v = (sub == 1) ? z1 : v;
        v = (sub == 2) ? z2 : v;
        v = (sub == 3) ? z3 : v;
        v = (sub == 4) ? z4 : v;
        v = (sub == 5) ? z5 : v;
        v = (sub == 6) ? z6 : v;
        v = (sub == 7) ? z7 : v;
        out[sample * 8 + sub] = v;
    }
}

extern "C" void kernel_launch(void* const* d_in, const int* in_sizes, int n_in,
                              void* d_out, int out_size, void* d_ws, size_t ws_size,
                              hipStream_t stream) {
    const float* x     = (const float*)d_in[0];
    const float* theta = (const float*)d_in[1];
    float* out = (float*)d_out;
    const int B = in_sizes[0] / 8;           // 16384
    const int threads_total = B * 16;        // 16 lanes per sample
    const int blocks = (threads_total + 255) / 256;
    hipLaunchKernelGGL(quantum_kernel, dim3(blocks), dim3(256), 0, stream,
                       x, theta, out, B);
}

// Round 2
// 68.566 us; speedup vs baseline: 1.6449x; 1.6449x over previous
//
#include <hip/hip_runtime.h>

#define PI_HALF_F 1.57079632679489661923f

// ---- lane-exchange primitives ----
// DPP quad_perm (VALU, free): masks 1,2,3
template<int CTRL>
__device__ __forceinline__ float dppq(float v) {
    return __int_as_float(__builtin_amdgcn_update_dpp(
        0, __float_as_int(v), CTRL, 0xF, 0xF, true));
}
#define DPP_XOR1 0xB1   // quad_perm [1,0,3,2]
#define DPP_XOR2 0x4E   // quad_perm [2,3,0,1]
#define DPP_XOR3 0x1B   // quad_perm [3,2,1,0]

// ds_swizzle xor (1 DS op): masks 4..15
template<int MASK>
__device__ __forceinline__ float swz(float v) {
    return __int_as_float(__builtin_amdgcn_ds_swizzle(
        __float_as_int(v), (MASK << 10) | 0x1F));
}

// ---- cross-lane 2x2 gate, partner = lane ^ MASK (DS swizzle) ----
template<int MASK>
__device__ __forceinline__ void lane_gate_sw(float (&re)[16], float (&im)[16],
                                             float car, float cai, float cbr, float cbi) {
#pragma unroll
    for (int r = 0; r < 16; ++r) {
        const float ar = re[r], ai = im[r];
        const float br = swz<MASK>(ar);
        const float bi = swz<MASK>(ai);
        re[r] = car * ar - cai * ai + cbr * br - cbi * bi;
        im[r] = car * ai + cai * ar + cbr * bi + cbi * br;
    }
}

// ---- cross-lane 2x2 gate via DPP quad_perm ----
template<int CTRL>
__device__ __forceinline__ void lane_gate_dpp(float (&re)[16], float (&im)[16],
                                              float car, float cai, float cbr, float cbi) {
#pragma unroll
    for (int r = 0; r < 16; ++r) {
        const float ar = re[r], ai = im[r];
        const float br = dppq<CTRL>(ar);
        const float bi = dppq<CTRL>(ai);
        re[r] = car * ar - cai * ai + cbr * br - cbi * bi;
        im[r] = car * ai + cai * ar + cbr * bi + cbi * br;
    }
}

// ---- in-register 2x2 gate: pairs (r, r^MASK); element hi = h_base ^ parity(r&FBITS)
// c0/d0 = self/partner coeffs for elements with parity(r&FBITS)==0,
// c1/d1 = for parity==1 (caller folds h_base into the c/d selection).
template<int MASK, int FBITS>
__device__ __forceinline__ void reg_gate(float (&re)[16], float (&im)[16],
        float c0r, float c0i, float d0r, float d0i,
        float c1r, float c1i, float d1r, float d1i) {
    constexpr int MSB = (MASK & 8) ? 8 : (MASK & 4) ? 4 : (MASK & 2) ? 2 : 1;
#pragma unroll
    for (int r = 0; r < 16; ++r) {
        if (r & MSB) continue;
        const int p = r ^ MASK;
        const bool f = __builtin_popcount(r & FBITS) & 1;  // compile-time
        const float ar = re[r], ai = im[r], br = re[p], bi = im[p];
        const float sAr = f ? c1r : c0r, sAi = f ? c1i : c0i;
        const float tAr = f ? d1r : d0r, tAi = f ? d1i : d0i;
        const float sBr = f ? c0r : c1r, sBi = f ? c0i : c1i;
        const float tBr = f ? d0r : d1r, tBi = f ? d0i : d1i;
        re[r] = sAr * ar - sAi * ai + tAr * br - tAi * bi;
        im[r] = sAr * ai + sAi * ar + tAr * bi + tAi * br;
        re[p] = sBr * br - sBi * bi + tBr * ar - tBi * ai;
        im[p] = sBr * bi + sBi * br + tBr * ai + tBi * ar;
    }
}

__global__ __launch_bounds__(256) void quantum_kernel(
    const float* __restrict__ x,
    const float* __restrict__ theta,
    float* __restrict__ out,
    int B)
{
    // ---- per-block: 16 shared Rot matrices in LDS ----
    __shared__ float g[16][8];  // [layer*8+q][u00r,u00i,u01r,u01i,u10r,u10i,u11r,u11i]
    const int t = threadIdx.x;
    if (t < 16) {
        const int layer = t >> 3, q = t & 7;
        const float phi = theta[(layer * 8 + q) * 3 + 0];
        const float th  = theta[(layer * 8 + q) * 3 + 1];
        const float om  = theta[(layer * 8 + q) * 3 + 2];
        const float ct = __cosf(0.5f * th), st = __sinf(0.5f * th);
        const float a = 0.5f * (phi + om), b = 0.5f * (phi - om);
        const float ca = __cosf(a), sa = __sinf(a);
        const float cb = __cosf(b), sb = __sinf(b);
        g[t][0] =  ct * ca;  g[t][1] = -ct * sa;
        g[t][2] = -st * cb;  g[t][3] = -st * sb;
        g[t][4] =  st * cb;  g[t][5] = -st * sb;
        g[t][6] =  ct * ca;  g[t][7] =  ct * sa;
    }
    __syncthreads();

    const int tid = blockIdx.x * 256 + t;
    const int sample = tid >> 4;
    if (sample >= B) return;
    const int sub = t & 15;  // lane bits s3..s0; physical p0=s3,p1=s2,p2=s1,p3=s0

    // ---- encoding: product state after RY(pi*x) ----
    const float4* xp = reinterpret_cast<const float4*>(x + sample * 8);
    const float4 xa = xp[0], xb = xp[1];
    float xs[8] = {xa.x, xa.y, xa.z, xa.w, xb.x, xb.y, xb.z, xb.w};
    float cq[8], sq[8];
#pragma unroll
    for (int q = 0; q < 8; ++q) {
        float v = fminf(fmaxf(xs[q], -1.0f), 1.0f) * PI_HALF_F;
        cq[q] = __cosf(v);
        sq[q] = __sinf(v);
    }
    const float fa0 = (sub & 8) ? sq[0] : cq[0];
    const float fa1 = (sub & 4) ? sq[1] : cq[1];
    const float fa2 = (sub & 2) ? sq[2] : cq[2];
    const float fa3 = (sub & 1) ? sq[3] : cq[3];
    const float plane = fa0 * fa1 * fa2 * fa3;

    float h45[4], h67[4];
#pragma unroll
    for (int k = 0; k < 4; ++k) {
        h45[k] = ((k & 2) ? sq[4] : cq[4]) * ((k & 1) ? sq[5] : cq[5]) * plane;
        h67[k] = ((k & 2) ? sq[6] : cq[6]) * ((k & 1) ? sq[7] : cq[7]);
    }
    float re[16], im[16];
#pragma unroll
    for (int r = 0; r < 16; ++r) { re[r] = h45[r >> 2] * h67[r & 3]; im[r] = 0.0f; }

#define LOADG(idx) \
    const float4 ga = *reinterpret_cast<const float4*>(&g[idx][0]); \
    const float4 gb = *reinterpret_cast<const float4*>(&g[idx][4]); \
    const float u00r = ga.x, u00i = ga.y, u01r = ga.z, u01i = ga.w; \
    const float u10r = gb.x, u10i = gb.y, u11r = gb.z, u11i = gb.w;

#define LANE_COEFFS(hi) \
    const float car = (hi) ? u11r : u00r, cai = (hi) ? u11i : u00i; \
    const float cbr = (hi) ? u10r : u01r, cbi = (hi) ? u10i : u01i;

    const bool s3 = (sub >> 3) & 1, s2 = (sub >> 2) & 1, s1 = (sub >> 1) & 1, s0 = sub & 1;
    const bool par4 = s3 ^ s2 ^ s1 ^ s0;

    // ================= LAYER 1 (M = I) =================
    { LOADG(0); LANE_COEFFS(s3); lane_gate_sw<8>(re, im, car, cai, cbr, cbi); }
    { LOADG(1); LANE_COEFFS(s2); lane_gate_sw<4>(re, im, car, cai, cbr, cbi); }
    { LOADG(2); LANE_COEFFS(s1); lane_gate_dpp<DPP_XOR2>(re, im, car, cai, cbr, cbi); }
    { LOADG(3); LANE_COEFFS(s0); lane_gate_dpp<DPP_XOR1>(re, im, car, cai, cbr, cbi); }
    { LOADG(4); reg_gate<8,8>(re, im, u00r,u00i, u01r,u01i, u11r,u11i, u10r,u10i); }
    { LOADG(5); reg_gate<4,4>(re, im, u00r,u00i, u01r,u01i, u11r,u11i, u10r,u10i); }
    { LOADG(6); reg_gate<2,2>(re, im, u00r,u00i, u01r,u01i, u11r,u11i, u10r,u10i); }
    { LOADG(7); reg_gate<1,1>(re, im, u00r,u00i, u01r,u01i, u11r,u11i, u10r,u10i); }
    // CNOT chain: pure GF(2) relabel -> zero instructions. M becomes prefix-sum.

    // ================= LAYER 2 (M = prefix) =================
    // gate on q pairs p ^ (e_q ^ e_{q+1}); hi = p0^..^pq
    { LOADG(8);  LANE_COEFFS(s3);            lane_gate_sw<12>(re, im, car, cai, cbr, cbi); }
    { LOADG(9);  LANE_COEFFS(s3 ^ s2);       lane_gate_sw<6>(re, im, car, cai, cbr, cbi); }
    { LOADG(10); LANE_COEFFS(s3 ^ s2 ^ s1);  lane_gate_dpp<DPP_XOR3>(re, im, car, cai, cbr, cbi); }
    // q3: partner = (lane^1, r^8); hi = par4 (uniform over regs)
    {
        LOADG(11); LANE_COEFFS(par4);
#pragma unroll
        for (int r = 0; r < 8; ++r) {
            const float a0r = re[r],     a0i = im[r];
            const float a1r = re[r + 8], a1i = im[r + 8];
            const float b0r = dppq<DPP_XOR1>(a1r);
            const float b0i = dppq<DPP_XOR1>(a1i);
            const float b1r = dppq<DPP_XOR1>(a0r);
            const float b1i = dppq<DPP_XOR1>(a0i);
            re[r]     = car * a0r - cai * a0i + cbr * b0r - cbi * b0i;
            im[r]     = car * a0i + cai * a0r + cbr * b0i + cbi * b0r;
            re[r + 8] = car * a1r - cai * a1i + cbr * b1r - cbi * b1i;
            im[r + 8] = car * a1i + cai * a1r + cbr * b1i + cbi * b1r;
        }
    }
    // q4..q7: in-register, element hi = par4 ^ parity(r & FBITS)
#define REG2_COEFFS() \
    const float c0r = par4 ? u11r : u00r, c0i = par4 ? u11i : u00i; \
    const float d0r = par4 ? u10r : u01r, d0i = par4 ? u10i : u01i; \
    const float c1r = par4 ? u00r : u11r, c1i = par4 ? u00i : u11i; \
    const float d1r = par4 ? u01r : u10r, d1i = par4 ? u01i : u10i;
    { LOADG(12); REG2_COEFFS(); reg_gate<12,8>(re, im, c0r,c0i,d0r,d0i,c1r,c1i,d1r,d1i); }
    { LOADG(13); REG2_COEFFS(); reg_gate<6,12>(re, im, c0r,c0i,d0r,d0i,c1r,c1i,d1r,d1i); }
    { LOADG(14); REG2_COEFFS(); reg_gate<3,14>(re, im, c0r,c0i,d0r,d0i,c1r,c1i,d1r,d1i); }
    { LOADG(15); REG2_COEFFS(); reg_gate<1,15>(re, im, c0r,c0i,d0r,d0i,c1r,c1i,d1r,d1i); }

    // ================= measurement under final M =================
    // M0=p0, M1=p1, M2=p0^p2, M3=p1^p3, M4=p0^p2^p4, M5=p1^p3^p5,
    // M6=p0^p2^p4^p6, M7=p1^p3^p5^p7  (p0=s3,p1=s2,p2=s1,p3=s0,p4=r3,p5=r2,p6=r1,p7=r0)
    float A = 0.f, B3 = 0.f, B2 = 0.f, B31 = 0.f, B20 = 0.f;
#pragma unroll
    for (int r = 0; r < 16; ++r) {
        const float P = re[r] * re[r] + im[r] * im[r];
        A   += P;
        B3  += (r & 8) ? -P : P;
        B2  += (r & 4) ? -P : P;
        B31 += ((((r >> 3) ^ (r >> 1)) & 1) ? -P : P);
        B20 += ((((r >> 2) ^ r) & 1) ? -P : P);
    }
    const bool sgnA = s3 ^ s1;  // p0^p2
    const bool sgnB = s2 ^ s0;  // p1^p3
    float z0 = s3   ? -A   : A;
    float z1 = s2   ? -A   : A;
    float z2 = sgnA ? -A   : A;
    float z3 = sgnB ? -A   : A;
    float z4 = sgnA ? -B3  : B3;
    float z5 = sgnB ? -B2  : B2;
    float z6 = sgnA ? -B31 : B31;
    float z7 = sgnB ? -B20 : B20;

    // butterfly over the 16-lane group: DPP for 1,2; ds_swizzle for 4,8
#define RED(z) \
    z += dppq<DPP_XOR1>(z); z += dppq<DPP_XOR2>(z); \
    z += swz<4>(z);         z += swz<8>(z);
    RED(z0) RED(z1) RED(z2) RED(z3) RED(z4) RED(z5) RED(z6) RED(z7)
#undef RED

    if (sub < 8) {
        float v = z0;
        v = (sub == 1) ? z1 : v;
        v = (sub == 2) ? z2 : v;
        v = (sub == 3) ? z3 : v;
        v = (sub == 4) ? z4 : v;
        v = (sub == 5) ? z5 : v;
        v = (sub == 6) ? z6 : v;
        v = (sub == 7) ? z7 : v;
        out[sample * 8 + sub] = v;
    }
}

extern "C" void kernel_launch(void* const* d_in, const int* in_sizes, int n_in,
                              void* d_out, int out_size, void* d_ws, size_t ws_size,
                              hipStream_t stream) {
    const float* x     = (const float*)d_in[0];
    const float* theta = (const float*)d_in[1];
    float* out = (float*)d_out;
    const int B = in_sizes[0] / 8;
    const int threads_total = B * 16;
    const int blocks = (threads_total + 255) / 256;
    hipLaunchKernelGGL(quantum_kernel, dim3(blocks), dim3(256), 0, stream,
                       x, theta, out, B);
}